// Round 10
// baseline (352.446 us; speedup 1.0000x reference)
//
#include <hip/hip_runtime.h>
#include <cstdint>
#include <cstddef>

// SplineNet: 2x SplineConv (K=3, K=5) + ELU, MLP head. N=100K, E=1.6M, D=64, C=16.
//
// R10: per-edge spline weights PRECOMPUTED in binsort as pre-1/deg-scaled fp16
// pairs, one record array per conv: recK[pos] = {src, half2(w0,w1)}. Gather
// loop: load rec, cndmask w->0 if past-end, load row, 2 splats, 4 pk_fma.
// No weight math, no cvt, no inv in gather. Rest = R9 (dual-stream quartile
// gather, MFMA GEMMs, MLP fused into gemm<5>, atomic-free partition CSR).
//
// ws: agg[N*320 h] 64MB | xh | h | staging[E int2] | rec3[E+4 int2] |
//     rec5[E+4 int2] | counts | partial | slotptr[N*4+1]  ~= 131 MB.

#define D_FEAT 64
#define AS_STRIDE 40
#define NB_MAX 1024
#define PART_B 128

typedef _Float16 half8v __attribute__((ext_vector_type(8)));
typedef _Float16 half4v __attribute__((ext_vector_type(4)));
typedef float f32x4 __attribute__((ext_vector_type(4)));

__device__ __forceinline__ float elu_f(float x) {
    return x > 0.f ? x : expm1f(x);
}

// ---------- merged prep: x->fp16 | dst-bucket count | W transposes ----------

__global__ __launch_bounds__(256) void prep_k(
    const float* __restrict__ x, const int* __restrict__ edst,
    const float* __restrict__ W1, const float* __restrict__ root1,
    const float* __restrict__ W2, const float* __restrict__ root2,
    const float* __restrict__ Wm1, const float* __restrict__ Wm2,
    _Float16* __restrict__ xh, unsigned int* __restrict__ counts,
    _Float16* __restrict__ Wt1, _Float16* __restrict__ Wt2,
    _Float16* __restrict__ Wm1t, _Float16* __restrict__ Wm2t,
    int E, int chunk, int NBUCKET, int total8, int cvtB)
{
    __shared__ unsigned int hist[NB_MAX];
    int b = blockIdx.x, t = threadIdx.x;
    if (b < cvtB) {
        int i = b * 256 + t;
        if (i < total8) {
            const float4* src = (const float4*)(x + (size_t)i * 8);
            float4 v0 = src[0], v1 = src[1];
            half8v hv = { (_Float16)v0.x, (_Float16)v0.y, (_Float16)v0.z, (_Float16)v0.w,
                          (_Float16)v1.x, (_Float16)v1.y, (_Float16)v1.z, (_Float16)v1.w };
            ((half8v*)xh)[i] = hv;
        }
        return;
    }
    if (b < cvtB + PART_B) {
        int bb = b - cvtB;
        for (int i = t; i < NBUCKET; i += 256) hist[i] = 0u;
        __syncthreads();
        int e0 = bb * chunk;
        int e1 = e0 + chunk; if (e1 > E) e1 = E;
        for (int e = e0 + t; e < e1; e += 256)
            atomicAdd(&hist[edst[e] >> 7], 1u);
        __syncthreads();
        for (int i = t; i < NBUCKET; i += 256)
            counts[(size_t)i * PART_B + bb] = hist[i];
        return;
    }
    int i = (b - cvtB - PART_B) * 256 + t;
    if (i < 64 * 256) {
        int n = i >> 8, k = i & 255;
        float v = (k < 192) ? W1[k * 64 + n] : root1[(k - 192) * 64 + n];
        Wt1[n * 256 + k] = (_Float16)v;
    } else if (i < 64 * 256 + 64 * 384) {
        int j = i - 64 * 256;
        int n = j / 384, k = j % 384;
        float v = (k < 320) ? W2[k * 64 + n] : root2[(k - 320) * 64 + n];
        Wt2[n * 384 + k] = (_Float16)v;
    } else if (i < 64 * 256 + 64 * 384 + 64 * 64) {
        int j = i - 64 * 256 - 64 * 384;
        int n = j >> 6, k = j & 63;
        Wm1t[n * 64 + k] = (_Float16)Wm1[k * 64 + n];
    } else if (i < 64 * 256 + 64 * 384 + 64 * 64 + 16 * 64) {
        int j = i - 64 * 256 - 64 * 384 - 64 * 64;
        int n = j >> 6, k = j & 63;
        Wm2t[n * 64 + k] = (_Float16)Wm2[k * 16 + n];
    }
}

// ---------- flat multi-block exclusive scan over counts[L] ----------

__global__ __launch_bounds__(256) void psum_k(
    const unsigned int* __restrict__ data, unsigned int* __restrict__ partial, int L)
{
    __shared__ unsigned int wsum[4];
    int i = blockIdx.x * 256 + threadIdx.x;
    int lane = threadIdx.x & 63, wid = threadIdx.x >> 6;
    unsigned int v = (i < L) ? data[i] : 0u;
    #pragma unroll
    for (int off = 32; off; off >>= 1) v += __shfl_xor(v, off);
    if (lane == 0) wsum[wid] = v;
    __syncthreads();
    if (threadIdx.x == 0)
        partial[blockIdx.x] = wsum[0] + wsum[1] + wsum[2] + wsum[3];
}

__global__ __launch_bounds__(512) void pscan_k(
    unsigned int* __restrict__ partial, int nb)
{
    __shared__ unsigned int wsum[8];
    int t = threadIdx.x, lane = t & 63, wid = t >> 6;
    unsigned int v = (t < nb) ? partial[t] : 0u;
    unsigned int orig = v;
    #pragma unroll
    for (int off = 1; off < 64; off <<= 1) {
        unsigned int s = __shfl_up(v, off);
        if (lane >= off) v += s;
    }
    if (lane == 63) wsum[wid] = v;
    __syncthreads();
    unsigned int add = 0;
    for (int i = 0; i < wid; ++i) add += wsum[i];
    if (t < nb) partial[t] = v + add - orig;
}

__global__ __launch_bounds__(256) void pwrite_k(
    unsigned int* __restrict__ data, const unsigned int* __restrict__ partial, int L)
{
    __shared__ unsigned int wsum[4];
    int i = blockIdx.x * 256 + threadIdx.x;
    int lane = threadIdx.x & 63, wid = threadIdx.x >> 6;
    unsigned int v = (i < L) ? data[i] : 0u;
    unsigned int orig = v;
    #pragma unroll
    for (int off = 1; off < 64; off <<= 1) {
        unsigned int s = __shfl_up(v, off);
        if (lane >= off) v += s;
    }
    if (lane == 63) wsum[wid] = v;
    __syncthreads();
    unsigned int add = partial[blockIdx.x];
    for (int w = 0; w < wid; ++w) add += wsum[w];
    if (i < L) data[i] = add + v - orig;
}

// ---------- place into bucket-grouped staging (LDS cursors) ----------

__global__ __launch_bounds__(256) void place_k(
    const int* __restrict__ esrc, const int* __restrict__ edst,
    const float* __restrict__ attr, const unsigned int* __restrict__ off,
    int2* __restrict__ staging, int E, int chunk, int NBUCKET)
{
    __shared__ unsigned int cur[NB_MAX];
    int t = threadIdx.x;
    for (int b = t; b < NBUCKET; b += 256)
        cur[b] = off[(size_t)b * PART_B + blockIdx.x];
    __syncthreads();
    int e0 = blockIdx.x * chunk;
    int e1 = e0 + chunk; if (e1 > E) e1 = E;
    for (int e = e0 + t; e < e1; e += 256) {
        int d = edst[e];
        unsigned int pos = atomicAdd(&cur[d >> 7], 1u);
        staging[pos] = make_int2(esrc[e] | ((d & 127) << 17), __float_as_int(attr[e]));
    }
}

// ---------- per-bucket sort by (node, quartile); emits slotptr + weight recs ----------
// Weights: degree-1 open B-spline pair for each conv, PRE-SCALED by 1/deg,
// stored as packed fp16 {w0,w1} next to src. One record array per conv.

__global__ __launch_bounds__(256) void binsort_k(
    const int2* __restrict__ staging, const unsigned int* __restrict__ off,
    unsigned int* __restrict__ slotptr,
    int2* __restrict__ rec3, int2* __restrict__ rec5,
    int N, int E, int NBUCKET)
{
    __shared__ unsigned int nh[512];
    __shared__ unsigned int curb[512];
    __shared__ unsigned int wsum[4];
    __shared__ float fdeg[128];
    int bkt = blockIdx.x, t = threadIdx.x;
    int node0 = bkt << 7;
    unsigned int start = off[(size_t)bkt * PART_B];
    unsigned int end = (bkt + 1 < NBUCKET) ? off[(size_t)(bkt + 1) * PART_B]
                                           : (unsigned int)E;
    nh[t] = 0u; nh[t + 256] = 0u;
    __syncthreads();
    for (unsigned int i = start + t; i < end; i += 256) {
        int2 r = staging[i];
        float p = __int_as_float(r.y);
        int q = (int)(p * 4.0f); q = q > 3 ? 3 : q;
        atomicAdd(&nh[(((r.x >> 17) & 127) << 2) | q], 1u);
    }
    __syncthreads();
    int lane = t & 63, wid = t >> 6;
    unsigned int v0 = nh[2 * t], v1 = nh[2 * t + 1];
    unsigned int pair = v0 + v1, inc = pair;
    #pragma unroll
    for (int o = 1; o < 64; o <<= 1) {
        unsigned int s = __shfl_up(inc, o);
        if (lane >= o) inc += s;
    }
    if (lane == 63) wsum[wid] = inc;
    __syncthreads();
    unsigned int wo = 0;
    for (int i = 0; i < wid; ++i) wo += wsum[i];
    unsigned int excl = wo + inc - pair;
    unsigned int b0 = start + excl, b1 = b0 + v0;
    curb[2 * t] = b0; curb[2 * t + 1] = b1;
    int j0 = 2 * t, j1 = 2 * t + 1;
    if (node0 + (j0 >> 2) < N) slotptr[(size_t)node0 * 4 + j0] = b0;
    if (node0 + (j1 >> 2) < N) slotptr[(size_t)node0 * 4 + j1] = b1;
    if (bkt == NBUCKET - 1 && t == 0) slotptr[(size_t)N * 4] = (unsigned int)E;
    // tail slack records (read-safe garbage guards for the dual-stream loop)
    if (bkt == NBUCKET - 1 && t < 4) {
        rec3[E + t] = make_int2(0, 0);
        rec5[E + t] = make_int2(0, 0);
    }
    __syncthreads();
    // per-node 1/deg from slot bases (before cursors advance)
    if (t < 128) {
        unsigned int s0 = curb[t << 2];
        unsigned int s1 = (t == 127) ? end : curb[(t << 2) + 4];
        fdeg[t] = 1.0f / fmaxf((float)(s1 - s0), 1.0f);
    }
    __syncthreads();
    for (unsigned int i = start + t; i < end; i += 256) {
        int2 r = staging[i];
        float p = __int_as_float(r.y);
        int q = (int)(p * 4.0f); q = q > 3 ? 3 : q;
        int nodeLocal = (r.x >> 17) & 127;
        unsigned int pos = atomicAdd(&curb[(nodeLocal << 2) | q], 1u);
        float fd = fdeg[nodeLocal];
        float fr5 = p * 4.0f - (float)q;
        float w15 = fr5 * fd, w05 = fd - w15;
        int i03 = q >> 1;
        float fr3 = p * 2.0f - (float)i03;
        float w13 = fr3 * fd, w03 = fd - w13;
        int src = r.x & 0x1FFFF;
        union { _Float16 h[2]; int i; } p5, p3;
        p5.h[0] = (_Float16)w05; p5.h[1] = (_Float16)w15;
        p3.h[0] = (_Float16)w03; p3.h[1] = (_Float16)w13;
        rec5[pos] = make_int2(src, p5.i);
        rec3[pos] = make_int2(src, p3.i);
    }
}

// ---------- gather: dual-stream quartile loop, precomputed fp16 weights ----------
// wave = node; lane = (edge-slot sub 0..3) x (16 half4 cols).
// phase 0: buckets {0,2}; phase 1: {1,3}. Per stream/iter: rec load, cndmask
// weights->0 past end, row load, 2 splats, 4 pk_fma. No inv (deg pre-folded).

template<int K>
__global__ __launch_bounds__(256) void gather_k(
    const _Float16* __restrict__ xin,
    const int2* __restrict__ rec,
    const unsigned int* __restrict__ slotptr,
    _Float16* __restrict__ agg, int N)
{
    int n = blockIdx.x * 4 + (threadIdx.x >> 6);
    int lane = threadIdx.x & 63;
    if (n >= N) return;
    int sub = lane >> 4;
    int col = (lane & 15) << 2;
    unsigned int sp[5];
    #pragma unroll
    for (int q = 0; q < 5; ++q) sp[q] = slotptr[(size_t)n * 4 + q];
    half4v acc[K];
    #pragma unroll
    for (int k = 0; k < K; ++k) acc[k] = (half4v){0, 0, 0, 0};

    #pragma unroll
    for (int ph = 0; ph < 2; ++ph) {
        const int qA = ph, qB = ph + 2;
        const int kA = (K == 5) ? qA : (qA >> 1);
        const int kB = (K == 5) ? qB : (qB >> 1);
        unsigned int iA = sp[qA], endA = sp[qA + 1];
        unsigned int iB = sp[qB], endB = sp[qB + 1];
        while (iA < endA || iB < endB) {
            unsigned int eA = iA + (unsigned int)sub;
            unsigned int eB = iB + (unsigned int)sub;
            int2 rA = rec[eA];                 // <= E+3: slack-guarded
            int2 rB = rec[eB];
            int wAi = (eA < endA) ? rA.y : 0;  // zero weights past end
            int wBi = (eB < endB) ? rB.y : 0;
            half4v rowA = *(const half4v*)(xin + (size_t)(unsigned)rA.x * D_FEAT + col);
            half4v rowB = *(const half4v*)(xin + (size_t)(unsigned)rB.x * D_FEAT + col);
            union { int i; _Float16 h[2]; } uA, uB;
            uA.i = wAi; uB.i = wBi;
            half4v w0A = {uA.h[0], uA.h[0], uA.h[0], uA.h[0]};
            half4v w1A = {uA.h[1], uA.h[1], uA.h[1], uA.h[1]};
            half4v w0B = {uB.h[0], uB.h[0], uB.h[0], uB.h[0]};
            half4v w1B = {uB.h[1], uB.h[1], uB.h[1], uB.h[1]};
            acc[kA]     += rowA * w0A;
            acc[kA + 1] += rowA * w1A;
            acc[kB]     += rowB * w0B;
            acc[kB + 1] += rowB * w1B;
            iA += 4; iB += 4;
        }
    }

    #pragma unroll
    for (int k = 0; k < K; ++k) {
        union { half4v h; int2 i; } u, s;
        u.h = acc[k];
        s.i.x = __shfl_xor(u.i.x, 16);
        s.i.y = __shfl_xor(u.i.y, 16);
        u.h += s.h;
        s.i.x = __shfl_xor(u.i.x, 32);
        s.i.y = __shfl_xor(u.i.y, 32);
        u.h += s.h;
        if (sub == 0)
            *(half4v*)(agg + ((size_t)n * K + k) * D_FEAT + col) = u.h;
    }
}

// ---------- MFMA GEMM (+ optional fused MLP head) ----------
// 128x64 tile / 256 threads; wave w = rows w*32..w*32+31.
// Frags (R4/R5-verified): A[m=lane&15][k=q*8+j], B from Wt[n=lane&15][k],
// C/D col=lane&15, row=q*4+reg.

template<int K, bool DO_MLP>
__global__ __launch_bounds__(256) void gemm_mfma(
    const _Float16* __restrict__ A,
    const _Float16* __restrict__ X,
    const _Float16* __restrict__ Wt,
    const float* __restrict__ bias,
    const _Float16* __restrict__ Wm1t,
    const float* __restrict__ bm1,
    const _Float16* __restrict__ Wm2t,
    const float* __restrict__ bm2,
    _Float16* __restrict__ outh,
    float* __restrict__ outf,
    int N)
{
    constexpr int lenA = K * 64;
    constexpr int Kd = lenA + D_FEAT;
    constexpr int SMEM_H = DO_MLP ? (128 * 72 * 2) : (128 * AS_STRIDE + 64 * AS_STRIDE);
    __shared__ _Float16 smem[SMEM_H];
    _Float16* As = smem;
    _Float16* Bs = smem + 128 * AS_STRIDE;

    int t = threadIdx.x;
    int row0 = blockIdx.x * 128;
    int w = t >> 6, lane = t & 63;
    int m16 = lane & 15, q = lane >> 4;

    f32x4 acc[2][4];
    #pragma unroll
    for (int rf = 0; rf < 2; ++rf)
        #pragma unroll
        for (int c = 0; c < 4; ++c) acc[rf][c] = (f32x4){0.f, 0.f, 0.f, 0.f};

    int srow = t >> 1;
    int skh  = (t & 1) * 16;
    int bn   = t >> 2;
    int bkq  = (t & 3) * 8;

    int grow = row0 + srow; if (grow >= N) grow = N - 1;
    const _Float16* arowA = A + (size_t)grow * lenA;
    const _Float16* arowX = X + (size_t)grow * D_FEAT;

    for (int kk = 0; kk < Kd; kk += 32) {
        const _Float16* src = (kk < lenA) ? (arowA + kk + skh)
                                          : (arowX + (kk - lenA) + skh);
        half8v a0 = *(const half8v*)(src);
        half8v a1 = *(const half8v*)(src + 8);
        half8v b0 = *(const half8v*)(Wt + (size_t)bn * Kd + kk + bkq);
        __syncthreads();
        *(half8v*)(&As[srow * AS_STRIDE + skh]) = a0;
        *(half8v*)(&As[srow * AS_STRIDE + skh + 8]) = a1;
        *(half8v*)(&Bs[bn * AS_STRIDE + bkq]) = b0;
        __syncthreads();
        half8v af0 = *(const half8v*)(&As[(w * 32 + m16) * AS_STRIDE + q * 8]);
        half8v af1 = *(const half8v*)(&As[(w * 32 + 16 + m16) * AS_STRIDE + q * 8]);
        #pragma unroll
        for (int c = 0; c < 4; ++c) {
            half8v bf = *(const half8v*)(&Bs[(c * 16 + m16) * AS_STRIDE + q * 8]);
            acc[0][c] = __builtin_amdgcn_mfma_f32_16x16x32_f16(af0, bf, acc[0][c], 0, 0, 0);
            acc[1][c] = __builtin_amdgcn_mfma_f32_16x16x32_f16(af1, bf, acc[1][c], 0, 0, 0);
        }
    }

    if (!DO_MLP) {
        #pragma unroll
        for (int rf = 0; rf < 2; ++rf)
            #pragma unroll
            for (int c = 0; c < 4; ++c) {
                int colg = c * 16 + m16;
                float bb = bias[colg];
                #pragma unroll
                for (int r = 0; r < 4; ++r) {
                    int rowg = row0 + w * 32 + rf * 16 + q * 4 + r;
                    if (rowg < N)
                        outh[(size_t)rowg * D_FEAT + colg] = (_Float16)elu_f(acc[rf][c][r] + bb);
                }
            }
        return;
    }

    // fused MLP head: per-wave self-contained rows (w*32..w*32+31)
    _Float16* Hs  = smem;               // [128][72]
    _Float16* Hs2 = smem + 128 * 72;    // [128][72]
    __syncthreads();                    // done with As/Bs
    #pragma unroll
    for (int rf = 0; rf < 2; ++rf)
        #pragma unroll
        for (int c = 0; c < 4; ++c) {
            int colg = c * 16 + m16;
            float bb = bias[colg];
            #pragma unroll
            for (int r = 0; r < 4; ++r)
                Hs[(w * 32 + rf * 16 + q * 4 + r) * 72 + colg] =
                    (_Float16)elu_f(acc[rf][c][r] + bb);
        }

    f32x4 acc3[2][4];
    #pragma unroll
    for (int rf = 0; rf < 2; ++rf)
        #pragma unroll
        for (int c = 0; c < 4; ++c) acc3[rf][c] = (f32x4){0.f, 0.f, 0.f, 0.f};
    #pragma unroll
    for (int kk = 0; kk < 64; kk += 32) {
        half8v af0 = *(const half8v*)(&Hs[(w * 32 + m16) * 72 + kk + q * 8]);
        half8v af1 = *(const half8v*)(&Hs[(w * 32 + 16 + m16) * 72 + kk + q * 8]);
        #pragma unroll
        for (int c = 0; c < 4; ++c) {
            half8v bf = *(const half8v*)(Wm1t + (size_t)(c * 16 + m16) * 64 + kk + q * 8);
            acc3[0][c] = __builtin_amdgcn_mfma_f32_16x16x32_f16(af0, bf, acc3[0][c], 0, 0, 0);
            acc3[1][c] = __builtin_amdgcn_mfma_f32_16x16x32_f16(af1, bf, acc3[1][c], 0, 0, 0);
        }
    }
    #pragma unroll
    for (int rf = 0; rf < 2; ++rf)
        #pragma unroll
        for (int c = 0; c < 4; ++c) {
            int colg = c * 16 + m16;
            float bb = bm1[colg];
            #pragma unroll
            for (int r = 0; r < 4; ++r)
                Hs2[(w * 32 + rf * 16 + q * 4 + r) * 72 + colg] =
                    (_Float16)fmaxf(acc3[rf][c][r] + bb, 0.f);
        }

    f32x4 acc4[2];
    acc4[0] = (f32x4){0.f, 0.f, 0.f, 0.f};
    acc4[1] = (f32x4){0.f, 0.f, 0.f, 0.f};
    #pragma unroll
    for (int kk = 0; kk < 64; kk += 32) {
        half8v af0 = *(const half8v*)(&Hs2[(w * 32 + m16) * 72 + kk + q * 8]);
        half8v af1 = *(const half8v*)(&Hs2[(w * 32 + 16 + m16) * 72 + kk + q * 8]);
        half8v bf = *(const half8v*)(Wm2t + (size_t)m16 * 64 + kk + q * 8);
        acc4[0] = __builtin_amdgcn_mfma_f32_16x16x32_f16(af0, bf, acc4[0], 0, 0, 0);
        acc4[1] = __builtin_amdgcn_mfma_f32_16x16x32_f16(af1, bf, acc4[1], 0, 0, 0);
    }
    float bb2 = bm2[m16];
    #pragma unroll
    for (int rf = 0; rf < 2; ++rf)
        #pragma unroll
        for (int r = 0; r < 4; ++r) {
            int rowg = row0 + w * 32 + rf * 16 + q * 4 + r;
            if (rowg < N)
                outf[(size_t)rowg * 16 + m16] = fmaxf(acc4[rf][r] + bb2, 0.f);
        }
}

extern "C" void kernel_launch(void* const* d_in, const int* in_sizes, int n_in,
                              void* d_out, int out_size, void* d_ws, size_t ws_size,
                              hipStream_t stream)
{
    const float* x     = (const float*)d_in[0];
    const int*   eidx  = (const int*)d_in[1];
    const float* attr  = (const float*)d_in[2];
    const float* W1    = (const float*)d_in[3];
    const float* root1 = (const float*)d_in[4];
    const float* b1    = (const float*)d_in[5];
    const float* W2    = (const float*)d_in[6];
    const float* root2 = (const float*)d_in[7];
    const float* b2    = (const float*)d_in[8];
    const float* Wm1   = (const float*)d_in[9];
    const float* bm1   = (const float*)d_in[10];
    const float* Wm2   = (const float*)d_in[11];
    const float* bm2   = (const float*)d_in[12];
    float* out = (float*)d_out;

    int N = in_sizes[0] / D_FEAT;
    int E = in_sizes[1] / 2;
    const int* esrc = eidx;
    const int* edst = eidx + E;
    int NBUCKET = (N + 127) >> 7;
    int chunk = (E + PART_B - 1) / PART_B;
    int L = NBUCKET * PART_B;
    int nbL = (L + 255) / 256;
    int total8 = N * D_FEAT / 8;
    int cvtB = (total8 + 255) / 256;
    int wElems = 64 * 256 + 64 * 384 + 64 * 64 + 16 * 64;
    int wB = (wElems + 255) / 256;

    _Float16* agg = (_Float16*)d_ws;
    _Float16* xh  = agg + (size_t)N * 5 * D_FEAT;
    _Float16* h   = xh + (size_t)N * D_FEAT;
    int2* staging = (int2*)(h + (size_t)N * D_FEAT);
    int2* rec3    = staging + E;
    int2* rec5    = rec3 + (E + 4);
    _Float16* Wt1 = (_Float16*)(rec5 + (E + 4));
    _Float16* Wt2 = Wt1 + 64 * 256;
    _Float16* Wm1t = Wt2 + 64 * 384;
    _Float16* Wm2t = Wm1t + 64 * 64;
    unsigned int* counts  = (unsigned int*)(Wm2t + 16 * 64);
    unsigned int* partial = counts + L;
    unsigned int* slotptr = partial + 512;

    dim3 blk(256);
    dim3 grid_w((N + 3) / 4);
    dim3 grid_g128((N + 127) / 128);

    prep_k<<<dim3(cvtB + PART_B + wB), blk, 0, stream>>>(
        x, edst, W1, root1, W2, root2, Wm1, Wm2,
        xh, counts, Wt1, Wt2, Wm1t, Wm2t, E, chunk, NBUCKET, total8, cvtB);

    psum_k<<<dim3(nbL), blk, 0, stream>>>(counts, partial, L);
    pscan_k<<<1, 512, 0, stream>>>(partial, nbL);
    pwrite_k<<<dim3(nbL), blk, 0, stream>>>(counts, partial, L);
    place_k<<<dim3(PART_B), blk, 0, stream>>>(esrc, edst, attr, counts, staging, E, chunk, NBUCKET);
    binsort_k<<<dim3(NBUCKET), blk, 0, stream>>>(staging, counts, slotptr, rec3, rec5, N, E, NBUCKET);

    // conv1: K=3
    gather_k<3><<<grid_w, blk, 0, stream>>>(xh, rec3, slotptr, agg, N);
    gemm_mfma<3, false><<<grid_g128, blk, 0, stream>>>(
        agg, xh, Wt1, b1, nullptr, nullptr, nullptr, nullptr, h, nullptr, N);

    // conv2: K=5 + fused MLP head
    gather_k<5><<<grid_w, blk, 0, stream>>>(h, rec5, slotptr, agg, N);
    gemm_mfma<5, true><<<grid_g128, blk, 0, stream>>>(
        agg, h, Wt2, b2, Wm1t, bm1, Wm2t, bm2, nullptr, out, N);
}

// Round 11
// 352.349 us; speedup vs baseline: 1.0003x; 1.0003x over previous
//
#include <hip/hip_runtime.h>
#include <cstdint>
#include <cstddef>

// SplineNet: 2x SplineConv (K=3, K=5) + ELU, MLP head. N=100K, E=1.6M, D=64, C=16.
//
// R11: gather = 4 CONCURRENT bucket streams (one per quartile): 4 independent
// rec loads + 4 row loads in flight per iteration (2x MLP vs R8/R10 dual
// phase), ~2.2 iters/node. Single rec array {src, half2(w15, fd)}: conv5
// weights (fd-w15, w15); conv3 derived from compile-time q:
// w13 = 0.5*w15 + (q&1)*0.5*fd, w03 = fd - w13. binsort writes 12.8 MB (not
// R10's 25.6). Rest = R10 (MFMA GEMMs, MLP fused in gemm<5>, partition CSR).
//
// ws: agg[N*320 h] 64MB | xh | h | staging[E int2] | rec[E int2] |
//     Wt1 | Wt2 | Wm1t | Wm2t | counts | partial | slotptr[N*4+1] ~= 118 MB.

#define D_FEAT 64
#define AS_STRIDE 40
#define NB_MAX 1024
#define PART_B 128

typedef _Float16 half8v __attribute__((ext_vector_type(8)));
typedef _Float16 half4v __attribute__((ext_vector_type(4)));
typedef float f32x4 __attribute__((ext_vector_type(4)));

__device__ __forceinline__ float elu_f(float x) {
    return x > 0.f ? x : expm1f(x);
}

// ---------- merged prep: x->fp16 | dst-bucket count | W transposes ----------

__global__ __launch_bounds__(256) void prep_k(
    const float* __restrict__ x, const int* __restrict__ edst,
    const float* __restrict__ W1, const float* __restrict__ root1,
    const float* __restrict__ W2, const float* __restrict__ root2,
    const float* __restrict__ Wm1, const float* __restrict__ Wm2,
    _Float16* __restrict__ xh, unsigned int* __restrict__ counts,
    _Float16* __restrict__ Wt1, _Float16* __restrict__ Wt2,
    _Float16* __restrict__ Wm1t, _Float16* __restrict__ Wm2t,
    int E, int chunk, int NBUCKET, int total8, int cvtB)
{
    __shared__ unsigned int hist[NB_MAX];
    int b = blockIdx.x, t = threadIdx.x;
    if (b < cvtB) {
        int i = b * 256 + t;
        if (i < total8) {
            const float4* src = (const float4*)(x + (size_t)i * 8);
            float4 v0 = src[0], v1 = src[1];
            half8v hv = { (_Float16)v0.x, (_Float16)v0.y, (_Float16)v0.z, (_Float16)v0.w,
                          (_Float16)v1.x, (_Float16)v1.y, (_Float16)v1.z, (_Float16)v1.w };
            ((half8v*)xh)[i] = hv;
        }
        return;
    }
    if (b < cvtB + PART_B) {
        int bb = b - cvtB;
        for (int i = t; i < NBUCKET; i += 256) hist[i] = 0u;
        __syncthreads();
        int e0 = bb * chunk;
        int e1 = e0 + chunk; if (e1 > E) e1 = E;
        for (int e = e0 + t; e < e1; e += 256)
            atomicAdd(&hist[edst[e] >> 7], 1u);
        __syncthreads();
        for (int i = t; i < NBUCKET; i += 256)
            counts[(size_t)i * PART_B + bb] = hist[i];
        return;
    }
    int i = (b - cvtB - PART_B) * 256 + t;
    if (i < 64 * 256) {
        int n = i >> 8, k = i & 255;
        float v = (k < 192) ? W1[k * 64 + n] : root1[(k - 192) * 64 + n];
        Wt1[n * 256 + k] = (_Float16)v;
    } else if (i < 64 * 256 + 64 * 384) {
        int j = i - 64 * 256;
        int n = j / 384, k = j % 384;
        float v = (k < 320) ? W2[k * 64 + n] : root2[(k - 320) * 64 + n];
        Wt2[n * 384 + k] = (_Float16)v;
    } else if (i < 64 * 256 + 64 * 384 + 64 * 64) {
        int j = i - 64 * 256 - 64 * 384;
        int n = j >> 6, k = j & 63;
        Wm1t[n * 64 + k] = (_Float16)Wm1[k * 64 + n];
    } else if (i < 64 * 256 + 64 * 384 + 64 * 64 + 16 * 64) {
        int j = i - 64 * 256 - 64 * 384 - 64 * 64;
        int n = j >> 6, k = j & 63;
        Wm2t[n * 64 + k] = (_Float16)Wm2[k * 16 + n];
    }
}

// ---------- flat multi-block exclusive scan over counts[L] ----------

__global__ __launch_bounds__(256) void psum_k(
    const unsigned int* __restrict__ data, unsigned int* __restrict__ partial, int L)
{
    __shared__ unsigned int wsum[4];
    int i = blockIdx.x * 256 + threadIdx.x;
    int lane = threadIdx.x & 63, wid = threadIdx.x >> 6;
    unsigned int v = (i < L) ? data[i] : 0u;
    #pragma unroll
    for (int off = 32; off; off >>= 1) v += __shfl_xor(v, off);
    if (lane == 0) wsum[wid] = v;
    __syncthreads();
    if (threadIdx.x == 0)
        partial[blockIdx.x] = wsum[0] + wsum[1] + wsum[2] + wsum[3];
}

__global__ __launch_bounds__(512) void pscan_k(
    unsigned int* __restrict__ partial, int nb)
{
    __shared__ unsigned int wsum[8];
    int t = threadIdx.x, lane = t & 63, wid = t >> 6;
    unsigned int v = (t < nb) ? partial[t] : 0u;
    unsigned int orig = v;
    #pragma unroll
    for (int off = 1; off < 64; off <<= 1) {
        unsigned int s = __shfl_up(v, off);
        if (lane >= off) v += s;
    }
    if (lane == 63) wsum[wid] = v;
    __syncthreads();
    unsigned int add = 0;
    for (int i = 0; i < wid; ++i) add += wsum[i];
    if (t < nb) partial[t] = v + add - orig;
}

__global__ __launch_bounds__(256) void pwrite_k(
    unsigned int* __restrict__ data, const unsigned int* __restrict__ partial, int L)
{
    __shared__ unsigned int wsum[4];
    int i = blockIdx.x * 256 + threadIdx.x;
    int lane = threadIdx.x & 63, wid = threadIdx.x >> 6;
    unsigned int v = (i < L) ? data[i] : 0u;
    unsigned int orig = v;
    #pragma unroll
    for (int off = 1; off < 64; off <<= 1) {
        unsigned int s = __shfl_up(v, off);
        if (lane >= off) v += s;
    }
    if (lane == 63) wsum[wid] = v;
    __syncthreads();
    unsigned int add = partial[blockIdx.x];
    for (int w = 0; w < wid; ++w) add += wsum[w];
    if (i < L) data[i] = add + v - orig;
}

// ---------- place into bucket-grouped staging (LDS cursors) ----------

__global__ __launch_bounds__(256) void place_k(
    const int* __restrict__ esrc, const int* __restrict__ edst,
    const float* __restrict__ attr, const unsigned int* __restrict__ off,
    int2* __restrict__ staging, int E, int chunk, int NBUCKET)
{
    __shared__ unsigned int cur[NB_MAX];
    int t = threadIdx.x;
    for (int b = t; b < NBUCKET; b += 256)
        cur[b] = off[(size_t)b * PART_B + blockIdx.x];
    __syncthreads();
    int e0 = blockIdx.x * chunk;
    int e1 = e0 + chunk; if (e1 > E) e1 = E;
    for (int e = e0 + t; e < e1; e += 256) {
        int d = edst[e];
        unsigned int pos = atomicAdd(&cur[d >> 7], 1u);
        staging[pos] = make_int2(esrc[e] | ((d & 127) << 17), __float_as_int(attr[e]));
    }
}

// ---------- per-bucket sort by (node, quartile); emits slotptr + rec ----------
// rec[pos] = {src, half2(w15, fd)} with w15 = frac5 * (1/deg), fd = 1/deg.
// conv5 weights: (fd - w15, w15). conv3 (q compile-time in gather):
// w13 = 0.5*w15 + (q&1)*0.5*fd, w03 = fd - w13.

__global__ __launch_bounds__(256) void binsort_k(
    const int2* __restrict__ staging, const unsigned int* __restrict__ off,
    unsigned int* __restrict__ slotptr, int2* __restrict__ rec,
    int N, int E, int NBUCKET)
{
    __shared__ unsigned int nh[512];
    __shared__ unsigned int curb[512];
    __shared__ unsigned int wsum[4];
    __shared__ float fdeg[128];
    int bkt = blockIdx.x, t = threadIdx.x;
    int node0 = bkt << 7;
    unsigned int start = off[(size_t)bkt * PART_B];
    unsigned int end = (bkt + 1 < NBUCKET) ? off[(size_t)(bkt + 1) * PART_B]
                                           : (unsigned int)E;
    nh[t] = 0u; nh[t + 256] = 0u;
    __syncthreads();
    for (unsigned int i = start + t; i < end; i += 256) {
        int2 r = staging[i];
        float p = __int_as_float(r.y);
        int q = (int)(p * 4.0f); q = q > 3 ? 3 : q;
        atomicAdd(&nh[(((r.x >> 17) & 127) << 2) | q], 1u);
    }
    __syncthreads();
    int lane = t & 63, wid = t >> 6;
    unsigned int v0 = nh[2 * t], v1 = nh[2 * t + 1];
    unsigned int pair = v0 + v1, inc = pair;
    #pragma unroll
    for (int o = 1; o < 64; o <<= 1) {
        unsigned int s = __shfl_up(inc, o);
        if (lane >= o) inc += s;
    }
    if (lane == 63) wsum[wid] = inc;
    __syncthreads();
    unsigned int wo = 0;
    for (int i = 0; i < wid; ++i) wo += wsum[i];
    unsigned int excl = wo + inc - pair;
    unsigned int b0 = start + excl, b1 = b0 + v0;
    curb[2 * t] = b0; curb[2 * t + 1] = b1;
    int j0 = 2 * t, j1 = 2 * t + 1;
    if (node0 + (j0 >> 2) < N) slotptr[(size_t)node0 * 4 + j0] = b0;
    if (node0 + (j1 >> 2) < N) slotptr[(size_t)node0 * 4 + j1] = b1;
    if (bkt == NBUCKET - 1 && t == 0) slotptr[(size_t)N * 4] = (unsigned int)E;
    __syncthreads();
    // per-node 1/deg from slot bases (before cursors advance)
    if (t < 128) {
        unsigned int s0 = curb[t << 2];
        unsigned int s1 = (t == 127) ? end : curb[(t << 2) + 4];
        fdeg[t] = 1.0f / fmaxf((float)(s1 - s0), 1.0f);
    }
    __syncthreads();
    for (unsigned int i = start + t; i < end; i += 256) {
        int2 r = staging[i];
        float p = __int_as_float(r.y);
        int q = (int)(p * 4.0f); q = q > 3 ? 3 : q;
        int nodeLocal = (r.x >> 17) & 127;
        unsigned int pos = atomicAdd(&curb[(nodeLocal << 2) | q], 1u);
        float fd = fdeg[nodeLocal];
        float fr5 = p * 4.0f - (float)q;
        float w15 = fr5 * fd;
        union { _Float16 h[2]; int i; } pr;
        pr.h[0] = (_Float16)w15; pr.h[1] = (_Float16)fd;
        rec[pos] = make_int2(r.x & 0x1FFFF, pr.i);
    }
}

// ---------- gather: 4 concurrent bucket streams, derived fp16 weights ----------
// wave = node; lane = (edge-slot sub 0..3) x (16 half4 cols). All 4 quartile
// buckets advance together: per iteration 4 independent rec loads then 4 row
// loads in flight. Finished streams clamp to rec[0] with zeroed weights.

template<int K>
__global__ __launch_bounds__(256) void gather_k(
    const _Float16* __restrict__ xin,
    const int2* __restrict__ rec,
    const unsigned int* __restrict__ slotptr,
    _Float16* __restrict__ agg, int N)
{
    int n = blockIdx.x * 4 + (threadIdx.x >> 6);
    int lane = threadIdx.x & 63;
    if (n >= N) return;
    int sub = lane >> 4;
    int col = (lane & 15) << 2;
    unsigned int sp[5];
    #pragma unroll
    for (int q = 0; q < 5; ++q) sp[q] = slotptr[(size_t)n * 4 + q];
    half4v acc[K];
    #pragma unroll
    for (int k = 0; k < K; ++k) acc[k] = (half4v){0, 0, 0, 0};

    unsigned int it[4], en[4];
    #pragma unroll
    for (int q = 0; q < 4; ++q) { it[q] = sp[q] + (unsigned int)sub; en[q] = sp[q + 1]; }

    while (it[0] < en[0] || it[1] < en[1] || it[2] < en[2] || it[3] < en[3]) {
        bool v[4];
        int2 r[4];
        #pragma unroll
        for (int q = 0; q < 4; ++q) {
            v[q] = it[q] < en[q];
            r[q] = rec[v[q] ? it[q] : 0u];          // 4 independent loads
        }
        half4v row[4];
        #pragma unroll
        for (int q = 0; q < 4; ++q)
            row[q] = *(const half4v*)(xin + (size_t)(unsigned)r[q].x * D_FEAT + col);
        #pragma unroll
        for (int q = 0; q < 4; ++q) {
            int wi = v[q] ? r[q].y : 0;
            union { int i; _Float16 h[2]; } u; u.i = wi;
            _Float16 w15 = u.h[0], fd = u.h[1];
            _Float16 w1, w0;
            if (K == 5) {
                w1 = w15;
                w0 = (_Float16)(fd - w15);
            } else {
                const _Float16 hf = (_Float16)0.5f;
                w1 = (q & 1) ? (_Float16)(hf * w15 + hf * fd) : (_Float16)(hf * w15);
                w0 = (_Float16)(fd - w1);
            }
            const int k0 = (K == 5) ? q : (q >> 1);
            half4v w0v = {w0, w0, w0, w0};
            half4v w1v = {w1, w1, w1, w1};
            acc[k0]     += row[q] * w0v;
            acc[k0 + 1] += row[q] * w1v;
            it[q] += 4;
        }
    }

    #pragma unroll
    for (int k = 0; k < K; ++k) {
        union { half4v h; int2 i; } u, s;
        u.h = acc[k];
        s.i.x = __shfl_xor(u.i.x, 16);
        s.i.y = __shfl_xor(u.i.y, 16);
        u.h += s.h;
        s.i.x = __shfl_xor(u.i.x, 32);
        s.i.y = __shfl_xor(u.i.y, 32);
        u.h += s.h;
        if (sub == 0)
            *(half4v*)(agg + ((size_t)n * K + k) * D_FEAT + col) = u.h;
    }
}

// ---------- MFMA GEMM (+ optional fused MLP head) ----------
// 128x64 tile / 256 threads; wave w = rows w*32..w*32+31.
// Frags (R4/R5-verified): A[m=lane&15][k=q*8+j], B from Wt[n=lane&15][k],
// C/D col=lane&15, row=q*4+reg.

template<int K, bool DO_MLP>
__global__ __launch_bounds__(256) void gemm_mfma(
    const _Float16* __restrict__ A,
    const _Float16* __restrict__ X,
    const _Float16* __restrict__ Wt,
    const float* __restrict__ bias,
    const _Float16* __restrict__ Wm1t,
    const float* __restrict__ bm1,
    const _Float16* __restrict__ Wm2t,
    const float* __restrict__ bm2,
    _Float16* __restrict__ outh,
    float* __restrict__ outf,
    int N)
{
    constexpr int lenA = K * 64;
    constexpr int Kd = lenA + D_FEAT;
    constexpr int SMEM_H = DO_MLP ? (128 * 72 * 2) : (128 * AS_STRIDE + 64 * AS_STRIDE);
    __shared__ _Float16 smem[SMEM_H];
    _Float16* As = smem;
    _Float16* Bs = smem + 128 * AS_STRIDE;

    int t = threadIdx.x;
    int row0 = blockIdx.x * 128;
    int w = t >> 6, lane = t & 63;
    int m16 = lane & 15, q = lane >> 4;

    f32x4 acc[2][4];
    #pragma unroll
    for (int rf = 0; rf < 2; ++rf)
        #pragma unroll
        for (int c = 0; c < 4; ++c) acc[rf][c] = (f32x4){0.f, 0.f, 0.f, 0.f};

    int srow = t >> 1;
    int skh  = (t & 1) * 16;
    int bn   = t >> 2;
    int bkq  = (t & 3) * 8;

    int grow = row0 + srow; if (grow >= N) grow = N - 1;
    const _Float16* arowA = A + (size_t)grow * lenA;
    const _Float16* arowX = X + (size_t)grow * D_FEAT;

    for (int kk = 0; kk < Kd; kk += 32) {
        const _Float16* src = (kk < lenA) ? (arowA + kk + skh)
                                          : (arowX + (kk - lenA) + skh);
        half8v a0 = *(const half8v*)(src);
        half8v a1 = *(const half8v*)(src + 8);
        half8v b0 = *(const half8v*)(Wt + (size_t)bn * Kd + kk + bkq);
        __syncthreads();
        *(half8v*)(&As[srow * AS_STRIDE + skh]) = a0;
        *(half8v*)(&As[srow * AS_STRIDE + skh + 8]) = a1;
        *(half8v*)(&Bs[bn * AS_STRIDE + bkq]) = b0;
        __syncthreads();
        half8v af0 = *(const half8v*)(&As[(w * 32 + m16) * AS_STRIDE + q * 8]);
        half8v af1 = *(const half8v*)(&As[(w * 32 + 16 + m16) * AS_STRIDE + q * 8]);
        #pragma unroll
        for (int c = 0; c < 4; ++c) {
            half8v bf = *(const half8v*)(&Bs[(c * 16 + m16) * AS_STRIDE + q * 8]);
            acc[0][c] = __builtin_amdgcn_mfma_f32_16x16x32_f16(af0, bf, acc[0][c], 0, 0, 0);
            acc[1][c] = __builtin_amdgcn_mfma_f32_16x16x32_f16(af1, bf, acc[1][c], 0, 0, 0);
        }
    }

    if (!DO_MLP) {
        #pragma unroll
        for (int rf = 0; rf < 2; ++rf)
            #pragma unroll
            for (int c = 0; c < 4; ++c) {
                int colg = c * 16 + m16;
                float bb = bias[colg];
                #pragma unroll
                for (int r = 0; r < 4; ++r) {
                    int rowg = row0 + w * 32 + rf * 16 + q * 4 + r;
                    if (rowg < N)
                        outh[(size_t)rowg * D_FEAT + colg] = (_Float16)elu_f(acc[rf][c][r] + bb);
                }
            }
        return;
    }

    // fused MLP head: per-wave self-contained rows (w*32..w*32+31)
    _Float16* Hs  = smem;               // [128][72]
    _Float16* Hs2 = smem + 128 * 72;    // [128][72]
    __syncthreads();                    // done with As/Bs
    #pragma unroll
    for (int rf = 0; rf < 2; ++rf)
        #pragma unroll
        for (int c = 0; c < 4; ++c) {
            int colg = c * 16 + m16;
            float bb = bias[colg];
            #pragma unroll
            for (int r = 0; r < 4; ++r)
                Hs[(w * 32 + rf * 16 + q * 4 + r) * 72 + colg] =
                    (_Float16)elu_f(acc[rf][c][r] + bb);
        }

    f32x4 acc3[2][4];
    #pragma unroll
    for (int rf = 0; rf < 2; ++rf)
        #pragma unroll
        for (int c = 0; c < 4; ++c) acc3[rf][c] = (f32x4){0.f, 0.f, 0.f, 0.f};
    #pragma unroll
    for (int kk = 0; kk < 64; kk += 32) {
        half8v af0 = *(const half8v*)(&Hs[(w * 32 + m16) * 72 + kk + q * 8]);
        half8v af1 = *(const half8v*)(&Hs[(w * 32 + 16 + m16) * 72 + kk + q * 8]);
        #pragma unroll
        for (int c = 0; c < 4; ++c) {
            half8v bf = *(const half8v*)(Wm1t + (size_t)(c * 16 + m16) * 64 + kk + q * 8);
            acc3[0][c] = __builtin_amdgcn_mfma_f32_16x16x32_f16(af0, bf, acc3[0][c], 0, 0, 0);
            acc3[1][c] = __builtin_amdgcn_mfma_f32_16x16x32_f16(af1, bf, acc3[1][c], 0, 0, 0);
        }
    }
    #pragma unroll
    for (int rf = 0; rf < 2; ++rf)
        #pragma unroll
        for (int c = 0; c < 4; ++c) {
            int colg = c * 16 + m16;
            float bb = bm1[colg];
            #pragma unroll
            for (int r = 0; r < 4; ++r)
                Hs2[(w * 32 + rf * 16 + q * 4 + r) * 72 + colg] =
                    (_Float16)fmaxf(acc3[rf][c][r] + bb, 0.f);
        }

    f32x4 acc4[2];
    acc4[0] = (f32x4){0.f, 0.f, 0.f, 0.f};
    acc4[1] = (f32x4){0.f, 0.f, 0.f, 0.f};
    #pragma unroll
    for (int kk = 0; kk < 64; kk += 32) {
        half8v af0 = *(const half8v*)(&Hs2[(w * 32 + m16) * 72 + kk + q * 8]);
        half8v af1 = *(const half8v*)(&Hs2[(w * 32 + 16 + m16) * 72 + kk + q * 8]);
        half8v bf = *(const half8v*)(Wm2t + (size_t)m16 * 64 + kk + q * 8);
        acc4[0] = __builtin_amdgcn_mfma_f32_16x16x32_f16(af0, bf, acc4[0], 0, 0, 0);
        acc4[1] = __builtin_amdgcn_mfma_f32_16x16x32_f16(af1, bf, acc4[1], 0, 0, 0);
    }
    float bb2 = bm2[m16];
    #pragma unroll
    for (int rf = 0; rf < 2; ++rf)
        #pragma unroll
        for (int r = 0; r < 4; ++r) {
            int rowg = row0 + w * 32 + rf * 16 + q * 4 + r;
            if (rowg < N)
                outf[(size_t)rowg * 16 + m16] = fmaxf(acc4[rf][r] + bb2, 0.f);
        }
}

extern "C" void kernel_launch(void* const* d_in, const int* in_sizes, int n_in,
                              void* d_out, int out_size, void* d_ws, size_t ws_size,
                              hipStream_t stream)
{
    const float* x     = (const float*)d_in[0];
    const int*   eidx  = (const int*)d_in[1];
    const float* attr  = (const float*)d_in[2];
    const float* W1    = (const float*)d_in[3];
    const float* root1 = (const float*)d_in[4];
    const float* b1    = (const float*)d_in[5];
    const float* W2    = (const float*)d_in[6];
    const float* root2 = (const float*)d_in[7];
    const float* b2    = (const float*)d_in[8];
    const float* Wm1   = (const float*)d_in[9];
    const float* bm1   = (const float*)d_in[10];
    const float* Wm2   = (const float*)d_in[11];
    const float* bm2   = (const float*)d_in[12];
    float* out = (float*)d_out;

    int N = in_sizes[0] / D_FEAT;
    int E = in_sizes[1] / 2;
    const int* esrc = eidx;
    const int* edst = eidx + E;
    int NBUCKET = (N + 127) >> 7;
    int chunk = (E + PART_B - 1) / PART_B;
    int L = NBUCKET * PART_B;
    int nbL = (L + 255) / 256;
    int total8 = N * D_FEAT / 8;
    int cvtB = (total8 + 255) / 256;
    int wElems = 64 * 256 + 64 * 384 + 64 * 64 + 16 * 64;
    int wB = (wElems + 255) / 256;

    _Float16* agg = (_Float16*)d_ws;
    _Float16* xh  = agg + (size_t)N * 5 * D_FEAT;
    _Float16* h   = xh + (size_t)N * D_FEAT;
    int2* staging = (int2*)(h + (size_t)N * D_FEAT);
    int2* rec     = staging + E;
    _Float16* Wt1 = (_Float16*)(rec + E);
    _Float16* Wt2 = Wt1 + 64 * 256;
    _Float16* Wm1t = Wt2 + 64 * 384;
    _Float16* Wm2t = Wm1t + 64 * 64;
    unsigned int* counts  = (unsigned int*)(Wm2t + 16 * 64);
    unsigned int* partial = counts + L;
    unsigned int* slotptr = partial + 512;

    dim3 blk(256);
    dim3 grid_w((N + 3) / 4);
    dim3 grid_g128((N + 127) / 128);

    prep_k<<<dim3(cvtB + PART_B + wB), blk, 0, stream>>>(
        x, edst, W1, root1, W2, root2, Wm1, Wm2,
        xh, counts, Wt1, Wt2, Wm1t, Wm2t, E, chunk, NBUCKET, total8, cvtB);

    psum_k<<<dim3(nbL), blk, 0, stream>>>(counts, partial, L);
    pscan_k<<<1, 512, 0, stream>>>(partial, nbL);
    pwrite_k<<<dim3(nbL), blk, 0, stream>>>(counts, partial, L);
    place_k<<<dim3(PART_B), blk, 0, stream>>>(esrc, edst, attr, counts, staging, E, chunk, NBUCKET);
    binsort_k<<<dim3(NBUCKET), blk, 0, stream>>>(staging, counts, slotptr, rec, N, E, NBUCKET);

    // conv1: K=3
    gather_k<3><<<grid_w, blk, 0, stream>>>(xh, rec, slotptr, agg, N);
    gemm_mfma<3, false><<<grid_g128, blk, 0, stream>>>(
        agg, xh, Wt1, b1, nullptr, nullptr, nullptr, nullptr, h, nullptr, N);

    // conv2: K=5 + fused MLP head
    gather_k<5><<<grid_w, blk, 0, stream>>>(h, rec, slotptr, agg, N);
    gemm_mfma<5, true><<<grid_g128, blk, 0, stream>>>(
        agg, h, Wt2, b2, Wm1t, bm1, Wm2t, bm2, nullptr, out, N);
}

// Round 12
// 328.164 us; speedup vs baseline: 1.0740x; 1.0737x over previous
//
#include <hip/hip_runtime.h>
#include <cstdint>
#include <cstddef>

// SplineNet: 2x SplineConv (K=3, K=5) + ELU, MLP head. N=100K, E=1.6M, D=64, C=16.
//
// R12: gather widened to 8-edge sub-groups: lane = sub(0..7) x col(0..7),
// half8 (16B) per lane, row = 8 lanes x 16B coalesced. 4 concurrent quartile
// streams -> 32 edges in flight, ~1.15 loop trips/node (was ~2.2). Epilogue:
// 3 shuffle-xor rounds (8,16,32) on packed fp16. Rest identical to R11
// (single rec {src, half2(w15,fd)}, derived conv3 weights, MFMA GEMMs, MLP
// fused in gemm<5>, atomic-free partition CSR).
//
// ws: agg[N*320 h] 64MB | xh | h | staging[E int2] | rec[E int2] |
//     Wt1 | Wt2 | Wm1t | Wm2t | counts | partial | slotptr[N*4+1] ~= 118 MB.

#define D_FEAT 64
#define AS_STRIDE 40
#define NB_MAX 1024
#define PART_B 128

typedef _Float16 half8v __attribute__((ext_vector_type(8)));
typedef _Float16 half4v __attribute__((ext_vector_type(4)));
typedef float f32x4 __attribute__((ext_vector_type(4)));

__device__ __forceinline__ float elu_f(float x) {
    return x > 0.f ? x : expm1f(x);
}

// ---------- merged prep: x->fp16 | dst-bucket count | W transposes ----------

__global__ __launch_bounds__(256) void prep_k(
    const float* __restrict__ x, const int* __restrict__ edst,
    const float* __restrict__ W1, const float* __restrict__ root1,
    const float* __restrict__ W2, const float* __restrict__ root2,
    const float* __restrict__ Wm1, const float* __restrict__ Wm2,
    _Float16* __restrict__ xh, unsigned int* __restrict__ counts,
    _Float16* __restrict__ Wt1, _Float16* __restrict__ Wt2,
    _Float16* __restrict__ Wm1t, _Float16* __restrict__ Wm2t,
    int E, int chunk, int NBUCKET, int total8, int cvtB)
{
    __shared__ unsigned int hist[NB_MAX];
    int b = blockIdx.x, t = threadIdx.x;
    if (b < cvtB) {
        int i = b * 256 + t;
        if (i < total8) {
            const float4* src = (const float4*)(x + (size_t)i * 8);
            float4 v0 = src[0], v1 = src[1];
            half8v hv = { (_Float16)v0.x, (_Float16)v0.y, (_Float16)v0.z, (_Float16)v0.w,
                          (_Float16)v1.x, (_Float16)v1.y, (_Float16)v1.z, (_Float16)v1.w };
            ((half8v*)xh)[i] = hv;
        }
        return;
    }
    if (b < cvtB + PART_B) {
        int bb = b - cvtB;
        for (int i = t; i < NBUCKET; i += 256) hist[i] = 0u;
        __syncthreads();
        int e0 = bb * chunk;
        int e1 = e0 + chunk; if (e1 > E) e1 = E;
        for (int e = e0 + t; e < e1; e += 256)
            atomicAdd(&hist[edst[e] >> 7], 1u);
        __syncthreads();
        for (int i = t; i < NBUCKET; i += 256)
            counts[(size_t)i * PART_B + bb] = hist[i];
        return;
    }
    int i = (b - cvtB - PART_B) * 256 + t;
    if (i < 64 * 256) {
        int n = i >> 8, k = i & 255;
        float v = (k < 192) ? W1[k * 64 + n] : root1[(k - 192) * 64 + n];
        Wt1[n * 256 + k] = (_Float16)v;
    } else if (i < 64 * 256 + 64 * 384) {
        int j = i - 64 * 256;
        int n = j / 384, k = j % 384;
        float v = (k < 320) ? W2[k * 64 + n] : root2[(k - 320) * 64 + n];
        Wt2[n * 384 + k] = (_Float16)v;
    } else if (i < 64 * 256 + 64 * 384 + 64 * 64) {
        int j = i - 64 * 256 - 64 * 384;
        int n = j >> 6, k = j & 63;
        Wm1t[n * 64 + k] = (_Float16)Wm1[k * 64 + n];
    } else if (i < 64 * 256 + 64 * 384 + 64 * 64 + 16 * 64) {
        int j = i - 64 * 256 - 64 * 384 - 64 * 64;
        int n = j >> 6, k = j & 63;
        Wm2t[n * 64 + k] = (_Float16)Wm2[k * 16 + n];
    }
}

// ---------- flat multi-block exclusive scan over counts[L] ----------

__global__ __launch_bounds__(256) void psum_k(
    const unsigned int* __restrict__ data, unsigned int* __restrict__ partial, int L)
{
    __shared__ unsigned int wsum[4];
    int i = blockIdx.x * 256 + threadIdx.x;
    int lane = threadIdx.x & 63, wid = threadIdx.x >> 6;
    unsigned int v = (i < L) ? data[i] : 0u;
    #pragma unroll
    for (int off = 32; off; off >>= 1) v += __shfl_xor(v, off);
    if (lane == 0) wsum[wid] = v;
    __syncthreads();
    if (threadIdx.x == 0)
        partial[blockIdx.x] = wsum[0] + wsum[1] + wsum[2] + wsum[3];
}

__global__ __launch_bounds__(512) void pscan_k(
    unsigned int* __restrict__ partial, int nb)
{
    __shared__ unsigned int wsum[8];
    int t = threadIdx.x, lane = t & 63, wid = t >> 6;
    unsigned int v = (t < nb) ? partial[t] : 0u;
    unsigned int orig = v;
    #pragma unroll
    for (int off = 1; off < 64; off <<= 1) {
        unsigned int s = __shfl_up(v, off);
        if (lane >= off) v += s;
    }
    if (lane == 63) wsum[wid] = v;
    __syncthreads();
    unsigned int add = 0;
    for (int i = 0; i < wid; ++i) add += wsum[i];
    if (t < nb) partial[t] = v + add - orig;
}

__global__ __launch_bounds__(256) void pwrite_k(
    unsigned int* __restrict__ data, const unsigned int* __restrict__ partial, int L)
{
    __shared__ unsigned int wsum[4];
    int i = blockIdx.x * 256 + threadIdx.x;
    int lane = threadIdx.x & 63, wid = threadIdx.x >> 6;
    unsigned int v = (i < L) ? data[i] : 0u;
    unsigned int orig = v;
    #pragma unroll
    for (int off = 1; off < 64; off <<= 1) {
        unsigned int s = __shfl_up(v, off);
        if (lane >= off) v += s;
    }
    if (lane == 63) wsum[wid] = v;
    __syncthreads();
    unsigned int add = partial[blockIdx.x];
    for (int w = 0; w < wid; ++w) add += wsum[w];
    if (i < L) data[i] = add + v - orig;
}

// ---------- place into bucket-grouped staging (LDS cursors) ----------

__global__ __launch_bounds__(256) void place_k(
    const int* __restrict__ esrc, const int* __restrict__ edst,
    const float* __restrict__ attr, const unsigned int* __restrict__ off,
    int2* __restrict__ staging, int E, int chunk, int NBUCKET)
{
    __shared__ unsigned int cur[NB_MAX];
    int t = threadIdx.x;
    for (int b = t; b < NBUCKET; b += 256)
        cur[b] = off[(size_t)b * PART_B + blockIdx.x];
    __syncthreads();
    int e0 = blockIdx.x * chunk;
    int e1 = e0 + chunk; if (e1 > E) e1 = E;
    for (int e = e0 + t; e < e1; e += 256) {
        int d = edst[e];
        unsigned int pos = atomicAdd(&cur[d >> 7], 1u);
        staging[pos] = make_int2(esrc[e] | ((d & 127) << 17), __float_as_int(attr[e]));
    }
}

// ---------- per-bucket sort by (node, quartile); emits slotptr + rec ----------
// rec[pos] = {src, half2(w15, fd)} with w15 = frac5 * (1/deg), fd = 1/deg.
// conv5 weights: (fd - w15, w15). conv3 (q compile-time in gather):
// w13 = 0.5*w15 + (q&1)*0.5*fd, w03 = fd - w13.

__global__ __launch_bounds__(256) void binsort_k(
    const int2* __restrict__ staging, const unsigned int* __restrict__ off,
    unsigned int* __restrict__ slotptr, int2* __restrict__ rec,
    int N, int E, int NBUCKET)
{
    __shared__ unsigned int nh[512];
    __shared__ unsigned int curb[512];
    __shared__ unsigned int wsum[4];
    __shared__ float fdeg[128];
    int bkt = blockIdx.x, t = threadIdx.x;
    int node0 = bkt << 7;
    unsigned int start = off[(size_t)bkt * PART_B];
    unsigned int end = (bkt + 1 < NBUCKET) ? off[(size_t)(bkt + 1) * PART_B]
                                           : (unsigned int)E;
    nh[t] = 0u; nh[t + 256] = 0u;
    __syncthreads();
    for (unsigned int i = start + t; i < end; i += 256) {
        int2 r = staging[i];
        float p = __int_as_float(r.y);
        int q = (int)(p * 4.0f); q = q > 3 ? 3 : q;
        atomicAdd(&nh[(((r.x >> 17) & 127) << 2) | q], 1u);
    }
    __syncthreads();
    int lane = t & 63, wid = t >> 6;
    unsigned int v0 = nh[2 * t], v1 = nh[2 * t + 1];
    unsigned int pair = v0 + v1, inc = pair;
    #pragma unroll
    for (int o = 1; o < 64; o <<= 1) {
        unsigned int s = __shfl_up(inc, o);
        if (lane >= o) inc += s;
    }
    if (lane == 63) wsum[wid] = inc;
    __syncthreads();
    unsigned int wo = 0;
    for (int i = 0; i < wid; ++i) wo += wsum[i];
    unsigned int excl = wo + inc - pair;
    unsigned int b0 = start + excl, b1 = b0 + v0;
    curb[2 * t] = b0; curb[2 * t + 1] = b1;
    int j0 = 2 * t, j1 = 2 * t + 1;
    if (node0 + (j0 >> 2) < N) slotptr[(size_t)node0 * 4 + j0] = b0;
    if (node0 + (j1 >> 2) < N) slotptr[(size_t)node0 * 4 + j1] = b1;
    if (bkt == NBUCKET - 1 && t == 0) slotptr[(size_t)N * 4] = (unsigned int)E;
    __syncthreads();
    // per-node 1/deg from slot bases (before cursors advance)
    if (t < 128) {
        unsigned int s0 = curb[t << 2];
        unsigned int s1 = (t == 127) ? end : curb[(t << 2) + 4];
        fdeg[t] = 1.0f / fmaxf((float)(s1 - s0), 1.0f);
    }
    __syncthreads();
    for (unsigned int i = start + t; i < end; i += 256) {
        int2 r = staging[i];
        float p = __int_as_float(r.y);
        int q = (int)(p * 4.0f); q = q > 3 ? 3 : q;
        int nodeLocal = (r.x >> 17) & 127;
        unsigned int pos = atomicAdd(&curb[(nodeLocal << 2) | q], 1u);
        float fd = fdeg[nodeLocal];
        float fr5 = p * 4.0f - (float)q;
        float w15 = fr5 * fd;
        union { _Float16 h[2]; int i; } pr;
        pr.h[0] = (_Float16)w15; pr.h[1] = (_Float16)fd;
        rec[pos] = make_int2(r.x & 0x1FFFF, pr.i);
    }
}

// ---------- gather: 4 streams x 8-edge subs, half8 lanes ----------
// wave = node; lane = sub(0..7) x col-group(0..7), 16B half8 per lane.
// All 4 quartile buckets advance together, 8 edges each per iteration.
// Finished streams clamp to rec[0] with zeroed weights (L1-hot).

template<int K>
__global__ __launch_bounds__(256) void gather_k(
    const _Float16* __restrict__ xin,
    const int2* __restrict__ rec,
    const unsigned int* __restrict__ slotptr,
    _Float16* __restrict__ agg, int N)
{
    int n = blockIdx.x * 4 + (threadIdx.x >> 6);
    int lane = threadIdx.x & 63;
    if (n >= N) return;
    int sub = lane >> 3;          // 0..7
    int col = (lane & 7) << 3;    // 0..56 halves (16B groups)
    uint4 sp0 = *(const uint4*)(slotptr + (size_t)n * 4);
    unsigned int sp4 = slotptr[(size_t)n * 4 + 4];
    unsigned int spA[5] = { sp0.x, sp0.y, sp0.z, sp0.w, sp4 };
    half8v acc[K];
    #pragma unroll
    for (int k = 0; k < K; ++k) acc[k] = (half8v){0, 0, 0, 0, 0, 0, 0, 0};

    unsigned int it[4], en[4];
    #pragma unroll
    for (int q = 0; q < 4; ++q) { it[q] = spA[q] + (unsigned int)sub; en[q] = spA[q + 1]; }

    while (it[0] < en[0] || it[1] < en[1] || it[2] < en[2] || it[3] < en[3]) {
        bool v[4];
        int2 r[4];
        #pragma unroll
        for (int q = 0; q < 4; ++q) {
            v[q] = it[q] < en[q];
            r[q] = rec[v[q] ? it[q] : 0u];          // 4 independent loads
        }
        half8v row[4];
        #pragma unroll
        for (int q = 0; q < 4; ++q)
            row[q] = *(const half8v*)(xin + (size_t)(unsigned)r[q].x * D_FEAT + col);
        #pragma unroll
        for (int q = 0; q < 4; ++q) {
            int wi = v[q] ? r[q].y : 0;
            union { int i; _Float16 h[2]; } u; u.i = wi;
            _Float16 w15 = u.h[0], fd = u.h[1];
            _Float16 w1, w0;
            if (K == 5) {
                w1 = w15;
                w0 = (_Float16)(fd - w15);
            } else {
                const _Float16 hf = (_Float16)0.5f;
                w1 = (q & 1) ? (_Float16)(hf * w15 + hf * fd) : (_Float16)(hf * w15);
                w0 = (_Float16)(fd - w1);
            }
            const int k0 = (K == 5) ? q : (q >> 1);
            half8v w0v = {w0, w0, w0, w0, w0, w0, w0, w0};
            half8v w1v = {w1, w1, w1, w1, w1, w1, w1, w1};
            acc[k0]     += row[q] * w0v;
            acc[k0 + 1] += row[q] * w1v;
            it[q] += 8;
        }
    }

    #pragma unroll
    for (int k = 0; k < K; ++k) {
        union { half8v h; int4 i; } u, s;
        u.h = acc[k];
        #pragma unroll
        for (int off = 8; off <= 32; off <<= 1) {
            s.i.x = __shfl_xor(u.i.x, off);
            s.i.y = __shfl_xor(u.i.y, off);
            s.i.z = __shfl_xor(u.i.z, off);
            s.i.w = __shfl_xor(u.i.w, off);
            u.h += s.h;
        }
        if (sub == 0)
            *(half8v*)(agg + ((size_t)n * K + k) * D_FEAT + col) = u.h;
    }
}

// ---------- MFMA GEMM (+ optional fused MLP head) ----------
// 128x64 tile / 256 threads; wave w = rows w*32..w*32+31.
// Frags (R4/R5-verified): A[m=lane&15][k=q*8+j], B from Wt[n=lane&15][k],
// C/D col=lane&15, row=q*4+reg.

template<int K, bool DO_MLP>
__global__ __launch_bounds__(256) void gemm_mfma(
    const _Float16* __restrict__ A,
    const _Float16* __restrict__ X,
    const _Float16* __restrict__ Wt,
    const float* __restrict__ bias,
    const _Float16* __restrict__ Wm1t,
    const float* __restrict__ bm1,
    const _Float16* __restrict__ Wm2t,
    const float* __restrict__ bm2,
    _Float16* __restrict__ outh,
    float* __restrict__ outf,
    int N)
{
    constexpr int lenA = K * 64;
    constexpr int Kd = lenA + D_FEAT;
    constexpr int SMEM_H = DO_MLP ? (128 * 72 * 2) : (128 * AS_STRIDE + 64 * AS_STRIDE);
    __shared__ _Float16 smem[SMEM_H];
    _Float16* As = smem;
    _Float16* Bs = smem + 128 * AS_STRIDE;

    int t = threadIdx.x;
    int row0 = blockIdx.x * 128;
    int w = t >> 6, lane = t & 63;
    int m16 = lane & 15, q = lane >> 4;

    f32x4 acc[2][4];
    #pragma unroll
    for (int rf = 0; rf < 2; ++rf)
        #pragma unroll
        for (int c = 0; c < 4; ++c) acc[rf][c] = (f32x4){0.f, 0.f, 0.f, 0.f};

    int srow = t >> 1;
    int skh  = (t & 1) * 16;
    int bn   = t >> 2;
    int bkq  = (t & 3) * 8;

    int grow = row0 + srow; if (grow >= N) grow = N - 1;
    const _Float16* arowA = A + (size_t)grow * lenA;
    const _Float16* arowX = X + (size_t)grow * D_FEAT;

    for (int kk = 0; kk < Kd; kk += 32) {
        const _Float16* src = (kk < lenA) ? (arowA + kk + skh)
                                          : (arowX + (kk - lenA) + skh);
        half8v a0 = *(const half8v*)(src);
        half8v a1 = *(const half8v*)(src + 8);
        half8v b0 = *(const half8v*)(Wt + (size_t)bn * Kd + kk + bkq);
        __syncthreads();
        *(half8v*)(&As[srow * AS_STRIDE + skh]) = a0;
        *(half8v*)(&As[srow * AS_STRIDE + skh + 8]) = a1;
        *(half8v*)(&Bs[bn * AS_STRIDE + bkq]) = b0;
        __syncthreads();
        half8v af0 = *(const half8v*)(&As[(w * 32 + m16) * AS_STRIDE + q * 8]);
        half8v af1 = *(const half8v*)(&As[(w * 32 + 16 + m16) * AS_STRIDE + q * 8]);
        #pragma unroll
        for (int c = 0; c < 4; ++c) {
            half8v bf = *(const half8v*)(&Bs[(c * 16 + m16) * AS_STRIDE + q * 8]);
            acc[0][c] = __builtin_amdgcn_mfma_f32_16x16x32_f16(af0, bf, acc[0][c], 0, 0, 0);
            acc[1][c] = __builtin_amdgcn_mfma_f32_16x16x32_f16(af1, bf, acc[1][c], 0, 0, 0);
        }
    }

    if (!DO_MLP) {
        #pragma unroll
        for (int rf = 0; rf < 2; ++rf)
            #pragma unroll
            for (int c = 0; c < 4; ++c) {
                int colg = c * 16 + m16;
                float bb = bias[colg];
                #pragma unroll
                for (int r = 0; r < 4; ++r) {
                    int rowg = row0 + w * 32 + rf * 16 + q * 4 + r;
                    if (rowg < N)
                        outh[(size_t)rowg * D_FEAT + colg] = (_Float16)elu_f(acc[rf][c][r] + bb);
                }
            }
        return;
    }

    // fused MLP head: per-wave self-contained rows (w*32..w*32+31)
    _Float16* Hs  = smem;               // [128][72]
    _Float16* Hs2 = smem + 128 * 72;    // [128][72]
    __syncthreads();                    // done with As/Bs
    #pragma unroll
    for (int rf = 0; rf < 2; ++rf)
        #pragma unroll
        for (int c = 0; c < 4; ++c) {
            int colg = c * 16 + m16;
            float bb = bias[colg];
            #pragma unroll
            for (int r = 0; r < 4; ++r)
                Hs[(w * 32 + rf * 16 + q * 4 + r) * 72 + colg] =
                    (_Float16)elu_f(acc[rf][c][r] + bb);
        }

    f32x4 acc3[2][4];
    #pragma unroll
    for (int rf = 0; rf < 2; ++rf)
        #pragma unroll
        for (int c = 0; c < 4; ++c) acc3[rf][c] = (f32x4){0.f, 0.f, 0.f, 0.f};
    #pragma unroll
    for (int kk = 0; kk < 64; kk += 32) {
        half8v af0 = *(const half8v*)(&Hs[(w * 32 + m16) * 72 + kk + q * 8]);
        half8v af1 = *(const half8v*)(&Hs[(w * 32 + 16 + m16) * 72 + kk + q * 8]);
        #pragma unroll
        for (int c = 0; c < 4; ++c) {
            half8v bf = *(const half8v*)(Wm1t + (size_t)(c * 16 + m16) * 64 + kk + q * 8);
            acc3[0][c] = __builtin_amdgcn_mfma_f32_16x16x32_f16(af0, bf, acc3[0][c], 0, 0, 0);
            acc3[1][c] = __builtin_amdgcn_mfma_f32_16x16x32_f16(af1, bf, acc3[1][c], 0, 0, 0);
        }
    }
    #pragma unroll
    for (int rf = 0; rf < 2; ++rf)
        #pragma unroll
        for (int c = 0; c < 4; ++c) {
            int colg = c * 16 + m16;
            float bb = bm1[colg];
            #pragma unroll
            for (int r = 0; r < 4; ++r)
                Hs2[(w * 32 + rf * 16 + q * 4 + r) * 72 + colg] =
                    (_Float16)fmaxf(acc3[rf][c][r] + bb, 0.f);
        }

    f32x4 acc4[2];
    acc4[0] = (f32x4){0.f, 0.f, 0.f, 0.f};
    acc4[1] = (f32x4){0.f, 0.f, 0.f, 0.f};
    #pragma unroll
    for (int kk = 0; kk < 64; kk += 32) {
        half8v af0 = *(const half8v*)(&Hs2[(w * 32 + m16) * 72 + kk + q * 8]);
        half8v af1 = *(const half8v*)(&Hs2[(w * 32 + 16 + m16) * 72 + kk + q * 8]);
        half8v bf = *(const half8v*)(Wm2t + (size_t)m16 * 64 + kk + q * 8);
        acc4[0] = __builtin_amdgcn_mfma_f32_16x16x32_f16(af0, bf, acc4[0], 0, 0, 0);
        acc4[1] = __builtin_amdgcn_mfma_f32_16x16x32_f16(af1, bf, acc4[1], 0, 0, 0);
    }
    float bb2 = bm2[m16];
    #pragma unroll
    for (int rf = 0; rf < 2; ++rf)
        #pragma unroll
        for (int r = 0; r < 4; ++r) {
            int rowg = row0 + w * 32 + rf * 16 + q * 4 + r;
            if (rowg < N)
                outf[(size_t)rowg * 16 + m16] = fmaxf(acc4[rf][r] + bb2, 0.f);
        }
}

extern "C" void kernel_launch(void* const* d_in, const int* in_sizes, int n_in,
                              void* d_out, int out_size, void* d_ws, size_t ws_size,
                              hipStream_t stream)
{
    const float* x     = (const float*)d_in[0];
    const int*   eidx  = (const int*)d_in[1];
    const float* attr  = (const float*)d_in[2];
    const float* W1    = (const float*)d_in[3];
    const float* root1 = (const float*)d_in[4];
    const float* b1    = (const float*)d_in[5];
    const float* W2    = (const float*)d_in[6];
    const float* root2 = (const float*)d_in[7];
    const float* b2    = (const float*)d_in[8];
    const float* Wm1   = (const float*)d_in[9];
    const float* bm1   = (const float*)d_in[10];
    const float* Wm2   = (const float*)d_in[11];
    const float* bm2   = (const float*)d_in[12];
    float* out = (float*)d_out;

    int N = in_sizes[0] / D_FEAT;
    int E = in_sizes[1] / 2;
    const int* esrc = eidx;
    const int* edst = eidx + E;
    int NBUCKET = (N + 127) >> 7;
    int chunk = (E + PART_B - 1) / PART_B;
    int L = NBUCKET * PART_B;
    int nbL = (L + 255) / 256;
    int total8 = N * D_FEAT / 8;
    int cvtB = (total8 + 255) / 256;
    int wElems = 64 * 256 + 64 * 384 + 64 * 64 + 16 * 64;
    int wB = (wElems + 255) / 256;

    _Float16* agg = (_Float16*)d_ws;
    _Float16* xh  = agg + (size_t)N * 5 * D_FEAT;
    _Float16* h   = xh + (size_t)N * D_FEAT;
    int2* staging = (int2*)(h + (size_t)N * D_FEAT);
    int2* rec     = staging + E;
    _Float16* Wt1 = (_Float16*)(rec + E);
    _Float16* Wt2 = Wt1 + 64 * 256;
    _Float16* Wm1t = Wt2 + 64 * 384;
    _Float16* Wm2t = Wm1t + 64 * 64;
    unsigned int* counts  = (unsigned int*)(Wm2t + 16 * 64);
    unsigned int* partial = counts + L;
    unsigned int* slotptr = partial + 512;

    dim3 blk(256);
    dim3 grid_w((N + 3) / 4);
    dim3 grid_g128((N + 127) / 128);

    prep_k<<<dim3(cvtB + PART_B + wB), blk, 0, stream>>>(
        x, edst, W1, root1, W2, root2, Wm1, Wm2,
        xh, counts, Wt1, Wt2, Wm1t, Wm2t, E, chunk, NBUCKET, total8, cvtB);

    psum_k<<<dim3(nbL), blk, 0, stream>>>(counts, partial, L);
    pscan_k<<<1, 512, 0, stream>>>(partial, nbL);
    pwrite_k<<<dim3(nbL), blk, 0, stream>>>(counts, partial, L);
    place_k<<<dim3(PART_B), blk, 0, stream>>>(esrc, edst, attr, counts, staging, E, chunk, NBUCKET);
    binsort_k<<<dim3(NBUCKET), blk, 0, stream>>>(staging, counts, slotptr, rec, N, E, NBUCKET);

    // conv1: K=3
    gather_k<3><<<grid_w, blk, 0, stream>>>(xh, rec, slotptr, agg, N);
    gemm_mfma<3, false><<<grid_g128, blk, 0, stream>>>(
        agg, xh, Wt1, b1, nullptr, nullptr, nullptr, nullptr, h, nullptr, N);

    // conv2: K=5 + fused MLP head
    gather_k<5><<<grid_w, blk, 0, stream>>>(h, rec, slotptr, agg, N);
    gemm_mfma<5, true><<<grid_g128, blk, 0, stream>>>(
        agg, h, Wt2, b2, Wm1t, bm1, Wm2t, bm2, nullptr, out, N);
}